// Round 7
// baseline (57.706 us; speedup 1.0000x reference)
//
#include <hip/hip_runtime.h>

#define BB 2
#define TT 512
#define HH 256
#define NBT (BB * TT)

#define C2LOG2E 2.8853900817779268f   // 2*log2(e): exp(2x)=2^(C*x)
#define LOG2E   1.4426950408889634f

__device__ __forceinline__ unsigned short f2bf(float f) {   // RNE float->bf16
    unsigned u = __float_as_uint(f);
    unsigned r = u + 0x7fffu + ((u >> 16) & 1u);
    return (unsigned short)(r >> 16);
}
__device__ __forceinline__ float bflo(unsigned u) { return __uint_as_float(u << 16); }
__device__ __forceinline__ float bfhi(unsigned u) { return __uint_as_float(u & 0xffff0000u); }

// ---------------------------------------------------------------------------
// Kernel 0 (prep): transpose Wq,Wk -> WT[h][o] fp32; convert K -> bf16.
// blocks 0..31: W transpose (64x64 tiles); blocks 32..287: K convert.
// ---------------------------------------------------------------------------
__global__ __launch_bounds__(256) void prep_kernel(
    const float* __restrict__ K, const float* __restrict__ Wq,
    const float* __restrict__ Wk,
    float* __restrict__ WqT, float* __restrict__ WkT,
    unsigned short* __restrict__ K16)
{
    int bid = blockIdx.x;
    int tid = threadIdx.x;
    if (bid < 32) {
        const float* W = (bid < 16) ? Wq : Wk;
        float* WT = (bid < 16) ? WqT : WkT;
        int tile = bid & 15;
        int o0 = (tile >> 2) * 64, h0 = (tile & 3) * 64;
        __shared__ float t_sh[64][65];
        int ty = tid >> 6, tx = tid & 63;
#pragma unroll
        for (int r = 0; r < 16; ++r) {
            int o = r * 4 + ty;
            t_sh[o][tx] = W[(o0 + o) * HH + h0 + tx];
        }
        __syncthreads();
#pragma unroll
        for (int r = 0; r < 16; ++r) {
            int h = r * 4 + ty;
            WT[(h0 + h) * HH + o0 + tx] = t_sh[tx][h];
        }
    } else {
        int i = (bid - 32) * 1024 + tid * 4;     // NBT*HH = 262144 elems
        float4 k4 = *reinterpret_cast<const float4*>(K + i);
        ushort4 o4;
        o4.x = f2bf(k4.x); o4.y = f2bf(k4.y); o4.z = f2bf(k4.z); o4.w = f2bf(k4.w);
        *reinterpret_cast<ushort4*>(K16 + i) = o4;
    }
}

// ---------------------------------------------------------------------------
// Kernel 1 (proj): Y = exp2(C * X @ WT)  via coalesced WT[h][o] loads.
// 512 threads: o4 = tid&63 (4 outs), sg = tid>>6 (row). 8 rows/block.
// Q-half -> Eq fp32 [bt][h]; K-half -> EkT16 bf16 [h8][bt][8] (LDS bounce).
// ---------------------------------------------------------------------------
__global__ __launch_bounds__(512) void proj_kernel(
    const float* __restrict__ Q, const float* __restrict__ K,
    const float* __restrict__ WqT, const float* __restrict__ WkT,
    float* __restrict__ Eq, unsigned short* __restrict__ EkT16)
{
    __shared__ float x_sh[8][HH];
    __shared__ unsigned short ek_sh[8][HH];

    int bid = blockIdx.x;
    bool isK = (bid >= 128);
    int bt0 = (isK ? bid - 128 : bid) * 8;
    const float* X = isK ? K : Q;
    const float* WT = isK ? WkT : WqT;
    int tid = threadIdx.x;
    int o4 = tid & 63, sg = tid >> 6;

    {   // stage 8 X rows (wave = one row, coalesced 1KB)
        int r = tid >> 6, h4 = tid & 63;
        *reinterpret_cast<float4*>(&x_sh[r][h4 * 4]) =
            *reinterpret_cast<const float4*>(X + (bt0 + r) * HH + h4 * 4);
    }
    __syncthreads();

    const float4* wt4 = reinterpret_cast<const float4*>(WT);
    float4 acc = {0.f, 0.f, 0.f, 0.f};
#pragma unroll 2
    for (int h4 = 0; h4 < 64; ++h4) {
        float4 x4 = *reinterpret_cast<const float4*>(&x_sh[sg][h4 * 4]);
        float4 w0 = wt4[(h4 * 4 + 0) * 64 + o4];
        float4 w1 = wt4[(h4 * 4 + 1) * 64 + o4];
        float4 w2 = wt4[(h4 * 4 + 2) * 64 + o4];
        float4 w3 = wt4[(h4 * 4 + 3) * 64 + o4];
        acc.x += x4.x * w0.x + x4.y * w1.x + x4.z * w2.x + x4.w * w3.x;
        acc.y += x4.x * w0.y + x4.y * w1.y + x4.z * w2.y + x4.w * w3.y;
        acc.z += x4.x * w0.z + x4.y * w1.z + x4.z * w2.z + x4.w * w3.z;
        acc.w += x4.x * w0.w + x4.y * w1.w + x4.z * w2.w + x4.w * w3.w;
    }
    float4 e;
    e.x = __builtin_amdgcn_exp2f(acc.x * C2LOG2E);
    e.y = __builtin_amdgcn_exp2f(acc.y * C2LOG2E);
    e.z = __builtin_amdgcn_exp2f(acc.z * C2LOG2E);
    e.w = __builtin_amdgcn_exp2f(acc.w * C2LOG2E);

    if (!isK) {
        *reinterpret_cast<float4*>(Eq + (bt0 + sg) * HH + o4 * 4) = e;
    } else {
        ushort4 u;
        u.x = f2bf(e.x); u.y = f2bf(e.y); u.z = f2bf(e.z); u.w = f2bf(e.w);
        *reinterpret_cast<ushort4*>(&ek_sh[sg][o4 * 4]) = u;
        __syncthreads();
        // scatter to EkT16[h8][bt][8]: thread -> (slab s_l, row bt_i, half)
        int s_l = tid >> 4, bt_i = (tid >> 1) & 7, half = tid & 1;
        uint2 val = *reinterpret_cast<const uint2*>(&ek_sh[bt_i][8 * s_l + 4 * half]);
        *reinterpret_cast<uint2*>(EkT16 + (s_l * NBT + bt0 + bt_i) * 8 + 4 * half) = val;
    }
}

// ---------------------------------------------------------------------------
// Kernel 2 (attn): scores (bf16 EkT) + softmax (no max-sub; scores bounded
// by 2*sum|v| ~ 26, exp2 safe in fp32) + context (bf16 K).
// One block per (b,t), 512 threads; block->t permuted for load balance.
// ---------------------------------------------------------------------------
__global__ __launch_bounds__(512, 8) void attn_kernel(
    const float* __restrict__ Eq, const unsigned short* __restrict__ EkT16,
    const unsigned short* __restrict__ K16, const float* __restrict__ v,
    float* __restrict__ ctx, float* __restrict__ alpha)
{
    __shared__ float eq_sh[HH];
    __shared__ float v2_sh[HH];
    __shared__ float al_sh[TT];
    __shared__ float red[8];
    __shared__ float4 cred[8][64];

    int bt = blockIdx.x;
    int b = bt / TT;
    int idx = bt % TT;
    int t = (idx < 256) ? idx : 767 - idx;
    int btr = b * TT + t;
    int tid = threadIdx.x;

    if (tid < HH) {
        eq_sh[tid] = Eq[btr * HH + tid];
        v2_sh[tid] = -2.0f * v[tid];
    }
    __syncthreads();

    // ---- score for s = tid ----
    float sc = 0.f;
    if (tid <= t) {
        const uint4* ek = reinterpret_cast<const uint4*>(EkT16) + (b * TT + tid);
        const float4* q4p = reinterpret_cast<const float4*>(eq_sh);
        const float4* v4p = reinterpret_cast<const float4*>(v2_sh);
#pragma unroll 2
        for (int h8 = 0; h8 < 32; ++h8) {
            uint4 kk = ek[h8 * NBT];             // lanes contiguous: 1KB/wave
            float4 qa = q4p[2 * h8], qb = q4p[2 * h8 + 1];
            float4 va = v4p[2 * h8], vb = v4p[2 * h8 + 1];
            float r0 = __builtin_amdgcn_rcpf(__builtin_fmaf(qa.x, bflo(kk.x), 1.f));
            float r1 = __builtin_amdgcn_rcpf(__builtin_fmaf(qa.y, bfhi(kk.x), 1.f));
            float r2 = __builtin_amdgcn_rcpf(__builtin_fmaf(qa.z, bflo(kk.y), 1.f));
            float r3 = __builtin_amdgcn_rcpf(__builtin_fmaf(qa.w, bfhi(kk.y), 1.f));
            float r4 = __builtin_amdgcn_rcpf(__builtin_fmaf(qb.x, bflo(kk.z), 1.f));
            float r5 = __builtin_amdgcn_rcpf(__builtin_fmaf(qb.y, bfhi(kk.z), 1.f));
            float r6 = __builtin_amdgcn_rcpf(__builtin_fmaf(qb.z, bflo(kk.w), 1.f));
            float r7 = __builtin_amdgcn_rcpf(__builtin_fmaf(qb.w, bfhi(kk.w), 1.f));
            sc = __builtin_fmaf(va.x, r0, sc);
            sc = __builtin_fmaf(va.y, r1, sc);
            sc = __builtin_fmaf(va.z, r2, sc);
            sc = __builtin_fmaf(va.w, r3, sc);
            sc = __builtin_fmaf(vb.x, r4, sc);
            sc = __builtin_fmaf(vb.y, r5, sc);
            sc = __builtin_fmaf(vb.z, r6, sc);
            sc = __builtin_fmaf(vb.w, r7, sc);
        }
    }

    // ---- softmax: sum only (scores bounded, no max-sub needed) ----
    float e = (tid <= t) ? __builtin_amdgcn_exp2f(sc * LOG2E) : 0.f;
    float ssum = e;
#pragma unroll
    for (int off = 32; off > 0; off >>= 1)
        ssum += __shfl_xor(ssum, off);
    if ((tid & 63) == 0) red[tid >> 6] = ssum;
    __syncthreads();
    float denom = (red[0] + red[1]) + (red[2] + red[3])
                + (red[4] + red[5]) + (red[6] + red[7]);
    float a0 = e * __builtin_amdgcn_rcpf(denom);

    al_sh[tid] = a0;
    alpha[btr * TT + tid] = a0;
    __syncthreads();

    // ---- context: hc = tid&63 (4 channels), sg = tid>>6 (s-stride 8) ----
    int hc = tid & 63, sg = tid >> 6;
    const uint2* kb = reinterpret_cast<const uint2*>(K16 + b * TT * HH);
    float4 acc4 = {0.f, 0.f, 0.f, 0.f};
    for (int s = sg; s <= t; s += 8) {
        uint2 kk = kb[s * 64 + hc];              // 8B/lane, coalesced
        float al = al_sh[s];                     // wave-uniform broadcast
        acc4.x = __builtin_fmaf(al, bflo(kk.x), acc4.x);
        acc4.y = __builtin_fmaf(al, bfhi(kk.x), acc4.y);
        acc4.z = __builtin_fmaf(al, bflo(kk.y), acc4.z);
        acc4.w = __builtin_fmaf(al, bfhi(kk.y), acc4.w);
    }
    cred[sg][hc] = acc4;
    __syncthreads();
    if (sg == 0) {
        float4 out = {0.f, 0.f, 0.f, 0.f};
#pragma unroll
        for (int g = 0; g < 8; ++g) {
            float4 c = cred[g][hc];
            out.x += c.x; out.y += c.y; out.z += c.z; out.w += c.w;
        }
        reinterpret_cast<float4*>(ctx + btr * HH)[hc] = out;
    }
}

extern "C" void kernel_launch(void* const* d_in, const int* in_sizes, int n_in,
                              void* d_out, int out_size, void* d_ws, size_t ws_size,
                              hipStream_t stream) {
    const float* Q  = (const float*)d_in[0];
    const float* K  = (const float*)d_in[1];
    const float* Wq = (const float*)d_in[2];
    const float* Wk = (const float*)d_in[3];
    const float* v  = (const float*)d_in[4];

    float* ctx   = (float*)d_out;                      // B*T*H
    float* alpha = (float*)d_out + NBT * HH;           // B*T*T

    // workspace layout (floats then ushorts): Eq | WqT | WkT | K16 | EkT16
    float* Eq  = (float*)d_ws;                         // NBT*HH fp32
    float* WqT = Eq + NBT * HH;                        // HH*HH fp32
    float* WkT = WqT + HH * HH;                        // HH*HH fp32
    unsigned short* K16   = (unsigned short*)(WkT + HH * HH);  // NBT*HH bf16
    unsigned short* EkT16 = K16 + NBT * HH;                    // NBT*HH bf16

    prep_kernel<<<288, 256, 0, stream>>>(K, Wq, Wk, WqT, WkT, K16);
    proj_kernel<<<256, 512, 0, stream>>>(Q, K, WqT, WkT, Eq, EkT16);
    attn_kernel<<<NBT, 512, 0, stream>>>(Eq, EkT16, K16, v, ctx, alpha);
}